// Round 3
// baseline (556.972 us; speedup 1.0000x reference)
//
#include <hip/hip_runtime.h>

#define TOBS  50
#define SDEC  100
#define HID   128
#define NG    512
#define EMB   64
#define MD    256
#define M2N   112
#define NZ    16
#define ROWS  16
#define KPAD  136    // shorts; 272B rows: 16B-aligned, 68 dw = 4*17 (odd mult) -> balanced b128 banks
#define H1PAD 264    // shorts; 132 dw = 4*33 (odd mult)

using bf16x8 = __attribute__((ext_vector_type(8))) short;
using f32x4  = __attribute__((ext_vector_type(4))) float;

struct alignas(16) SMem {
  unsigned short h[2][ROWS * KPAD];                                   // 8704 B  h double buffer
  union { unsigned int offsb[TOBS][ROWS]; uint4 b5f[64][5]; } u2;     // 5120 B  enc offs (bf16x2) / dec Wr frags
  float offlast[ROWS][2];                                             //  128 B
  union { unsigned short h1[ROWS * H1PAD]; float4 cl[NG]; } u;        // 8448 B  MLP hidden / fused consts
  float delta[ROWS][2];                                               //  128 B
};

__device__ __forceinline__ unsigned int rnd16(float x){
  return __builtin_bit_cast(unsigned int, x) + 0x8000u;   // round-half-up to bf16 (in high 16)
}
__device__ __forceinline__ unsigned int pkbf(float a, float b){
  // low16 = bf16(a), high16 = bf16(b): one v_perm after two adds
  return __builtin_amdgcn_perm(rnd16(b), rnd16(a), 0x07060302u);
}
__device__ __forceinline__ unsigned short bfs(float x){ return (unsigned short)(rnd16(x) >> 16); }
__device__ __forceinline__ float fsig(float x){
  return __builtin_amdgcn_rcpf(1.0f + __expf(-x));
}
__device__ __forceinline__ float ftanh(float x){
  return 2.0f * __builtin_amdgcn_rcpf(1.0f + __expf(-2.0f * x)) - 1.0f;
}
__device__ __forceinline__ bf16x8 pack8(const float* p){
  float4 a = *(const float4*)p;
  float4 b = *(const float4*)(p + 4);
  uint4 u;
  u.x = pkbf(a.x, a.y); u.y = pkbf(a.z, a.w);
  u.z = pkbf(b.x, b.y); u.w = pkbf(b.z, b.w);
  return __builtin_bit_cast(bf16x8, u);
}

extern "C" __global__ void __launch_bounds__(512, 4)
seqgen(const float* __restrict__ obs,
       const float* __restrict__ We,    const float* __restrict__ be,
       const float* __restrict__ Wih_e, const float* __restrict__ Whh_e, const float* __restrict__ b_e,
       const float* __restrict__ Wm1,   const float* __restrict__ bm1,
       const float* __restrict__ Wm2,   const float* __restrict__ bm2,
       const float* __restrict__ Wd,    const float* __restrict__ bd,
       const float* __restrict__ Wih_d, const float* __restrict__ Whh_d, const float* __restrict__ b_d,
       const float* __restrict__ Wr,    const float* __restrict__ br,
       const float* __restrict__ z,     float* __restrict__ out)
{
  __shared__ SMem sm;
  const int tid  = threadIdx.x;
  const int lane = tid & 63;
  const int jq   = tid >> 6;          // wave id = hidden column tile (0..7)
  const int cc   = lane & 15;
  const int qd   = lane >> 4;
  const bool q0  = (qd == 0);
  const int R0   = blockIdx.x * ROWS;
  const int colj = jq * 16 + cc;
  const unsigned int one_q0 = q0 ? 0x3F80u : 0u;   // bf16(1.0) in k=2 slot

  // ---------------- prep ----------------
  for (int i = tid; i < TOBS * ROWS; i += 512){
    int t = i >> 4, row = i & 15;
    const float* ob = obs + (size_t)(R0 + row) * (TOBS * 2) + t * 2;
    float o0 = ob[0], o1 = ob[1];
    if (t){ o0 -= ob[-2]; o1 -= ob[-1]; }
    sm.u2.offsb[t][row] = pkbf(o0, o1);
    if (t == TOBS - 1){ sm.offlast[row][0] = o0; sm.offlast[row][1] = o1; }
  }
  for (int i = tid; i < ROWS * KPAD / 2; i += 512)
    ((unsigned int*)&sm.h[0][0])[i] = 0u;
  {
    const float* wr = Wih_e + tid * EMB;
    float w0 = 0.f, w1 = 0.f, bb = b_e[tid];
    for (int e = 0; e < EMB; ++e){
      float w = wr[e];
      w0 += w * We[e*2]; w1 += w * We[e*2+1]; bb += w * be[e];
    }
    sm.u.cl[tid] = make_float4(bb, w0, w1, 0.f);
  }
  __syncthreads();

  // input/bias B-fragments {w0,w1,bc} at k=0,1,2 (qd==0 lanes)
  bf16x8 b5x[4];
  #pragma unroll
  for (int g = 0; g < 4; ++g){
    float4 v = sm.u.cl[g*128 + colj];
    uint4 w;
    w.x = q0 ? pkbf(v.y, v.z) : 0u;
    w.y = q0 ? (rnd16(v.x) >> 16) : 0u;
    w.z = 0u; w.w = 0u;
    b5x[g] = __builtin_bit_cast(bf16x8, w);
  }
  // encoder Whh in registers
  bf16x8 bfr[4][4];
  #pragma unroll
  for (int kt = 0; kt < 4; ++kt)
    #pragma unroll
    for (int g = 0; g < 4; ++g)
      bfr[g][kt] = pack8(Whh_e + (size_t)(g*128 + colj) * HID + kt*32 + qd*8);

  f32x4 zz = {0.f, 0.f, 0.f, 0.f};    // persistent zero C-operand
  float cst[4] = {0.f, 0.f, 0.f, 0.f};

  // ================= encoder: 50 steps =================
  for (int t = 0; t < TOBS; ++t){
    const int par = t & 1;
    unsigned int po = sm.u2.offsb[t][cc];
    uint4 a5i; a5i.x = q0 ? po : 0u; a5i.y = one_q0; a5i.z = 0u; a5i.w = 0u;
    bf16x8 af5 = __builtin_bit_cast(bf16x8, a5i);

    bf16x8 af[4];
    #pragma unroll
    for (int kt = 0; kt < 4; ++kt)
      af[kt] = *(const bf16x8*)&sm.h[par][cc*KPAD + kt*32 + qd*8];

    f32x4 acc[4];
    #pragma unroll
    for (int g = 0; g < 4; ++g)
      acc[g] = __builtin_amdgcn_mfma_f32_16x16x32_bf16(af5, b5x[g], zz, 0, 0, 0);
    #pragma unroll
    for (int kt = 0; kt < 4; ++kt)
      #pragma unroll
      for (int g = 0; g < 4; ++g)
        acc[g] = __builtin_amdgcn_mfma_f32_16x16x32_bf16(af[kt], bfr[g][kt], acc[g], 0, 0, 0);

    unsigned short* hn = &sm.h[par ^ 1][0];
    #pragma unroll
    for (int r = 0; r < 4; ++r){
      float iv = acc[0][r], fv = acc[1][r], gv = acc[2][r], ov = acc[3][r];
      float cn = fsig(fv) * cst[r] + fsig(iv) * ftanh(gv);
      cst[r] = cn;
      float hh = fsig(ov) * ftanh(cn);
      hn[(qd*4 + r)*KPAD + colj] = bfs(hh);
    }
    __syncthreads();
  }
  // hF in sm.h[0]

  // ================= MLP =================
  {
    bf16x8 af[4];
    #pragma unroll
    for (int kt = 0; kt < 4; ++kt)
      af[kt] = *(const bf16x8*)&sm.h[0][cc*KPAD + kt*32 + qd*8];
    f32x4 a1[2];
    #pragma unroll
    for (int t2 = 0; t2 < 2; ++t2){
      const int n = jq*32 + t2*16 + cc;
      float b = bm1[n];
      f32x4 a = {b, b, b, b};
      const float* wrow = Wm1 + (size_t)n * HID;
      #pragma unroll
      for (int kt = 0; kt < 4; ++kt)
        a = __builtin_amdgcn_mfma_f32_16x16x32_bf16(af[kt], pack8(wrow + kt*32 + qd*8), a, 0,0,0);
      a1[t2] = a;
    }
    #pragma unroll
    for (int t2 = 0; t2 < 2; ++t2)
      #pragma unroll
      for (int r = 0; r < 4; ++r){
        float v = a1[t2][r]; v = v > 0.f ? v : 0.f;
        sm.u.h1[(qd*4 + r)*H1PAD + jq*32 + t2*16 + cc] = bfs(v);
      }
  }
  __syncthreads();
  {
    bf16x8 af2[8];
    #pragma unroll
    for (int kt = 0; kt < 8; ++kt)
      af2[kt] = *(const bf16x8*)&sm.u.h1[cc*H1PAD + kt*32 + qd*8];
    if (jq < 7){
      const int n = jq*16 + cc;
      float b = bm2[n];
      f32x4 a2 = {b, b, b, b};
      const float* wrow = Wm2 + (size_t)n * MD;
      #pragma unroll
      for (int kt = 0; kt < 8; ++kt)
        a2 = __builtin_amdgcn_mfma_f32_16x16x32_bf16(af2[kt], pack8(wrow + kt*32 + qd*8), a2, 0,0,0);
      #pragma unroll
      for (int r = 0; r < 4; ++r){
        float v = a2[r]; v = v > 0.f ? v : 0.f;
        sm.h[0][(qd*4 + r)*KPAD + jq*16 + cc] = bfs(v);
      }
    }
    if (tid < ROWS * NZ){
      int row = tid >> 4, nz = tid & 15;
      sm.h[0][row*KPAD + M2N + nz] = bfs(z[(size_t)(R0 + row)*NZ + nz]);
    }
  }
  __syncthreads();   // dh ready in h[0]; h1/cl region reusable

  // ================= decoder prep =================
  {
    const float* wr = Wih_d + tid * EMB;
    float w0 = 0.f, w1 = 0.f, bb = b_d[tid];
    for (int e = 0; e < EMB; ++e){
      float w = wr[e];
      w0 += w * Wd[e*2]; w1 += w * Wd[e*2+1]; bb += w * bd[e];
    }
    sm.u.cl[tid] = make_float4(bb, w0, w1, 0.f);
  }
  const float br0 = br[0], br1 = br[1];
  const float brc = (cc == 0) ? br0 : br1;
  if (jq == 0){
    // build readout Wr fragments -> LDS; compute delta = off_last - (Wr.dh + br)
    uint4 bq[4];
    #pragma unroll
    for (int kt = 0; kt < 4; ++kt){
      bf16x8 f = pack8(Wr + (size_t)(cc & 1)*HID + kt*32 + qd*8);
      uint4 uu = __builtin_bit_cast(uint4, f);
      if (cc >= 2){ uu.x = 0u; uu.y = 0u; uu.z = 0u; uu.w = 0u; }
      bq[kt] = uu;
      sm.u2.b5f[lane][kt] = uu;
    }
    bf16x8 afd[4];
    #pragma unroll
    for (int kt = 0; kt < 4; ++kt)
      afd[kt] = *(const bf16x8*)&sm.h[0][cc*KPAD + kt*32 + qd*8];
    f32x4 a5 = zz;
    #pragma unroll
    for (int kt = 0; kt < 4; ++kt)
      a5 = __builtin_amdgcn_mfma_f32_16x16x32_bf16(afd[kt], __builtin_bit_cast(bf16x8, bq[kt]), a5, 0,0,0);
    if (cc < 2){
      #pragma unroll
      for (int r = 0; r < 4; ++r){
        int row = qd*4 + r;
        sm.delta[row][cc] = sm.offlast[row][cc] - (a5[r] + brc);
      }
    }
  }
  __syncthreads();

  // decoder consts: b5x' (feedback-folded bias) and bfr' = Whh_d + u0(x)Wr0 + u1(x)Wr1
  float w0g[4], w1g[4];
  #pragma unroll
  for (int g = 0; g < 4; ++g){
    float4 v = sm.u.cl[g*128 + colj];
    w0g[g] = v.y; w1g[g] = v.z;
    float bcp = v.x + v.y*br0 + v.z*br1;
    uint4 w;
    w.x = q0 ? pkbf(v.y, v.z) : 0u;
    w.y = q0 ? (rnd16(bcp) >> 16) : 0u;
    w.z = 0u; w.w = 0u;
    b5x[g] = __builtin_bit_cast(bf16x8, w);
  }
  #pragma unroll
  for (int kt = 0; kt < 4; ++kt){
    const int kb = kt*32 + qd*8;
    float4 wa = *(const float4*)(Wr + kb),       wb2 = *(const float4*)(Wr + kb + 4);
    float4 va = *(const float4*)(Wr + HID + kb), vb2 = *(const float4*)(Wr + HID + kb + 4);
    #pragma unroll
    for (int g = 0; g < 4; ++g){
      const float* p = Whh_d + (size_t)(g*128 + colj) * HID + kb;
      float4 fa = *(const float4*)p, fb = *(const float4*)(p + 4);
      uint4 uu;
      uu.x = pkbf(fa.x + w0g[g]*wa.x  + w1g[g]*va.x,  fa.y + w0g[g]*wa.y  + w1g[g]*va.y);
      uu.y = pkbf(fa.z + w0g[g]*wa.z  + w1g[g]*va.z,  fa.w + w0g[g]*wa.w  + w1g[g]*va.w);
      uu.z = pkbf(fb.x + w0g[g]*wb2.x + w1g[g]*vb2.x, fb.y + w0g[g]*wb2.y + w1g[g]*vb2.y);
      uu.w = pkbf(fb.z + w0g[g]*wb2.z + w1g[g]*vb2.z, fb.w + w0g[g]*wb2.w + w1g[g]*vb2.w);
      bfr[g][kt] = __builtin_bit_cast(bf16x8, uu);
    }
  }
  // step-0 delta A-fragment; steady-state A-fragment = {0,0,1}
  float2 dv = *(const float2*)&sm.delta[cc][0];
  uint4 a5c; a5c.x = 0u; a5c.y = one_q0; a5c.z = 0u; a5c.w = 0u;
  uint4 a5d = a5c; a5d.x = q0 ? pkbf(dv.x, dv.y) : 0u;
  const bf16x8 af5c = __builtin_bit_cast(bf16x8, a5c);
  bf16x8 af5cur = __builtin_bit_cast(bf16x8, a5d);

  float cum[4] = {0.f, 0.f, 0.f, 0.f};
  if (jq == 0 && cc < 2){
    #pragma unroll
    for (int r = 0; r < 4; ++r)
      cum[r] = obs[(size_t)(R0 + qd*4 + r)*(TOBS*2) + (TOBS-1)*2 + cc];
  }
  #pragma unroll
  for (int r = 0; r < 4; ++r) cst[r] = 0.f;
  __syncthreads();

  // ================= decoder: 100 steps =================
  for (int s = 0; s < SDEC; ++s){
    const int par = s & 1;
    bf16x8 af[4];
    #pragma unroll
    for (int kt = 0; kt < 4; ++kt)
      af[kt] = *(const bf16x8*)&sm.h[par][cc*KPAD + kt*32 + qd*8];

    f32x4 acc[4];
    #pragma unroll
    for (int g = 0; g < 4; ++g)
      acc[g] = __builtin_amdgcn_mfma_f32_16x16x32_bf16(af5cur, b5x[g], zz, 0, 0, 0);
    #pragma unroll
    for (int kt = 0; kt < 4; ++kt)
      #pragma unroll
      for (int g = 0; g < 4; ++g)
        acc[g] = __builtin_amdgcn_mfma_f32_16x16x32_bf16(af[kt], bfr[g][kt], acc[g], 0, 0, 0);

    if (jq == 0 && s > 0){
      f32x4 a5 = {brc, brc, brc, brc};
      #pragma unroll
      for (int kt = 0; kt < 4; ++kt)
        a5 = __builtin_amdgcn_mfma_f32_16x16x32_bf16(af[kt],
               __builtin_bit_cast(bf16x8, sm.u2.b5f[lane][kt]), a5, 0, 0, 0);
      if (cc < 2){
        #pragma unroll
        for (int r = 0; r < 4; ++r){
          cum[r] += a5[r];
          out[((size_t)(R0 + qd*4 + r)*SDEC + (s-1))*2 + cc] = cum[r];
        }
      }
    }

    unsigned short* hn = &sm.h[par ^ 1][0];
    #pragma unroll
    for (int r = 0; r < 4; ++r){
      float iv = acc[0][r], fv = acc[1][r], gv = acc[2][r], ov = acc[3][r];
      float cn = fsig(fv) * cst[r] + fsig(iv) * ftanh(gv);
      cst[r] = cn;
      float hh = fsig(ov) * ftanh(cn);
      hn[(qd*4 + r)*KPAD + colj] = bfs(hh);
    }
    af5cur = af5c;
    __syncthreads();
  }

  // epilogue: pred[S-1] from h[0]
  if (jq == 0){
    bf16x8 af[4];
    #pragma unroll
    for (int kt = 0; kt < 4; ++kt)
      af[kt] = *(const bf16x8*)&sm.h[0][cc*KPAD + kt*32 + qd*8];
    f32x4 a5 = {brc, brc, brc, brc};
    #pragma unroll
    for (int kt = 0; kt < 4; ++kt)
      a5 = __builtin_amdgcn_mfma_f32_16x16x32_bf16(af[kt],
             __builtin_bit_cast(bf16x8, sm.u2.b5f[lane][kt]), a5, 0, 0, 0);
    if (cc < 2){
      #pragma unroll
      for (int r = 0; r < 4; ++r){
        cum[r] += a5[r];
        out[((size_t)(R0 + qd*4 + r)*SDEC + (SDEC-1))*2 + cc] = cum[r];
      }
    }
  }
}

extern "C" void kernel_launch(void* const* d_in, const int* in_sizes, int n_in,
                              void* d_out, int out_size, void* d_ws, size_t ws_size,
                              hipStream_t stream) {
  (void)in_sizes; (void)n_in; (void)d_ws; (void)ws_size; (void)out_size;
  const float* obs   = (const float*)d_in[0];
  // d_in[1] = num_steps (100), compile-time constant here
  const float* We    = (const float*)d_in[2];
  const float* be    = (const float*)d_in[3];
  const float* Wih_e = (const float*)d_in[4];
  const float* Whh_e = (const float*)d_in[5];
  const float* b_e   = (const float*)d_in[6];
  const float* Wm1   = (const float*)d_in[7];
  const float* bm1   = (const float*)d_in[8];
  const float* Wm2   = (const float*)d_in[9];
  const float* bm2   = (const float*)d_in[10];
  const float* Wd    = (const float*)d_in[11];
  const float* bd    = (const float*)d_in[12];
  const float* Wih_d = (const float*)d_in[13];
  const float* Whh_d = (const float*)d_in[14];
  const float* b_d   = (const float*)d_in[15];
  const float* Wr    = (const float*)d_in[16];
  const float* br    = (const float*)d_in[17];
  const float* zz    = (const float*)d_in[18];
  hipLaunchKernelGGL(seqgen, dim3(8192 / ROWS), dim3(512), 0, stream,
                     obs, We, be, Wih_e, Whh_e, b_e, Wm1, bm1, Wm2, bm2,
                     Wd, bd, Wih_d, Whh_d, b_d, Wr, br, zz, (float*)d_out);
}

// Round 5
// 441.816 us; speedup vs baseline: 1.2606x; 1.2606x over previous
//
#include <hip/hip_runtime.h>

#define TOBS  50
#define SDEC  100
#define HID   128
#define EMB   64
#define MD    256
#define M2N   112
#define NZ    16
#define ROWS  32
#define KPAD  136    // shorts; 68 dw = 4 mod 32 -> 2-way (free) on b128 row reads
#define H1PAD 264    // shorts; 132 dw = 4 mod 32 -> 2-way

#define L2E   1.4426950408889634f
#define TL2E  2.8853900817779268f

using bf16x8 = __attribute__((ext_vector_type(8))) short;
using f32x4  = __attribute__((ext_vector_type(4))) float;

struct alignas(16) SMem {
  unsigned short h[2][ROWS * KPAD];        // 17408 B  h double buffer (bf16)
  union {
    float xch[8][2][2][64][4];             // 32768 B  sig_f/sig_o exchange (f32, lane-contig)
    float4 cl[512];                        //  8192 B  fused input consts
    unsigned short h1[ROWS * H1PAD];       // 16896 B  MLP hidden
  } u;
  unsigned int offsb[TOBS][ROWS];          //  6400 B  encoder offsets (bf16x2)
  float offlast[ROWS][2];                  //   256 B
  uint4 b5f[64][4];                        //  4096 B  readout Wr B-fragments
  float delta[ROWS][2];                    //   256 B  decoder step-0 correction
};

__device__ __forceinline__ unsigned int rnd16(float x){
  return __builtin_bit_cast(unsigned int, x) + 0x8000u;
}
__device__ __forceinline__ unsigned int pkbf(float a, float b){
  return __builtin_amdgcn_perm(rnd16(b), rnd16(a), 0x07060302u);
}
__device__ __forceinline__ unsigned short bfs(float x){ return (unsigned short)(rnd16(x) >> 16); }
__device__ __forceinline__ float rcpf(float x){ return __builtin_amdgcn_rcpf(x); }
__device__ __forceinline__ float ex2(float x){ return __builtin_amdgcn_exp2f(x); }
__device__ __forceinline__ bf16x8 pack8(const float* p){
  float4 a = *(const float4*)p;
  float4 b = *(const float4*)(p + 4);
  uint4 u;
  u.x = pkbf(a.x, a.y); u.y = pkbf(a.z, a.w);
  u.z = pkbf(b.x, b.y); u.w = pkbf(b.z, b.w);
  return __builtin_bit_cast(bf16x8, u);
}

extern "C" __global__ void __launch_bounds__(1024, 4)
seqgen(const float* __restrict__ obs,
       const float* __restrict__ We,    const float* __restrict__ be,
       const float* __restrict__ Wih_e, const float* __restrict__ Whh_e, const float* __restrict__ b_e,
       const float* __restrict__ Wm1,   const float* __restrict__ bm1,
       const float* __restrict__ Wm2,   const float* __restrict__ bm2,
       const float* __restrict__ Wd,    const float* __restrict__ bd,
       const float* __restrict__ Wih_d, const float* __restrict__ Whh_d, const float* __restrict__ b_d,
       const float* __restrict__ Wr,    const float* __restrict__ br,
       const float* __restrict__ z,     float* __restrict__ out)
{
  __shared__ SMem sm;
  const int tid  = threadIdx.x;
  const int lane = tid & 63;
  const int wv   = tid >> 6;        // 0..15
  const int j    = wv >> 1;         // column tile 0..7
  const int gs   = wv & 1;          // 0: gates {i,g}   1: gates {f,o}
  const int cc   = lane & 15;
  const int qd   = lane >> 4;
  const bool q0  = (qd == 0);
  const int R0   = blockIdx.x * ROWS;
  const int colj = j * 16 + cc;
  const int ga0  = gs ? 1 : 0;      // gate row-block indices
  const int ga1  = gs ? 3 : 2;
  const unsigned int one_q0 = q0 ? 0x3F80u : 0u;

  // ---------------- prep ----------------
  for (int i = tid; i < TOBS * ROWS; i += 1024){
    int t = i >> 5, row = i & 31;
    const float* ob = obs + (size_t)(R0 + row) * (TOBS * 2) + t * 2;
    float o0 = ob[0], o1 = ob[1];
    if (t){ o0 -= ob[-2]; o1 -= ob[-1]; }
    sm.offsb[t][row] = pkbf(o0, o1);
    if (t == TOBS - 1){ sm.offlast[row][0] = o0; sm.offlast[row][1] = o1; }
  }
  for (int i = tid; i < ROWS * KPAD / 2; i += 1024)
    ((unsigned int*)&sm.h[0][0])[i] = 0u;
  if (tid < 512){
    const float* wr = Wih_e + tid * EMB;
    float w0 = 0.f, w1 = 0.f, bb = b_e[tid];
    for (int e = 0; e < EMB; ++e){
      float w = wr[e];
      w0 += w * We[e*2]; w1 += w * We[e*2+1]; bb += w * be[e];
    }
    sm.u.cl[tid] = make_float4(bb, w0, w1, 0.f);
  }
  __syncthreads();

  // input/bias B-fragments for this wave's 2 gates
  bf16x8 b5x[2];
  {
    float4 v0 = sm.u.cl[ga0*128 + colj];
    float4 v1 = sm.u.cl[ga1*128 + colj];
    uint4 w;
    w.x = q0 ? pkbf(v0.y, v0.z) : 0u; w.y = q0 ? (rnd16(v0.x) >> 16) : 0u; w.z = 0u; w.w = 0u;
    b5x[0] = __builtin_bit_cast(bf16x8, w);
    w.x = q0 ? pkbf(v1.y, v1.z) : 0u; w.y = q0 ? (rnd16(v1.x) >> 16) : 0u;
    b5x[1] = __builtin_bit_cast(bf16x8, w);
  }
  // encoder Whh (2 gates only) in registers
  bf16x8 bfr[2][4];
  #pragma unroll
  for (int kt = 0; kt < 4; ++kt){
    bfr[0][kt] = pack8(Whh_e + (size_t)(ga0*128 + colj) * HID + kt*32 + qd*8);
    bfr[1][kt] = pack8(Whh_e + (size_t)(ga1*128 + colj) * HID + kt*32 + qd*8);
  }
  f32x4 zz4 = {0.f, 0.f, 0.f, 0.f};
  float cst[2][4];
  #pragma unroll
  for (int rg = 0; rg < 2; ++rg)
    #pragma unroll
    for (int r = 0; r < 4; ++r) cst[rg][r] = 0.f;
  __syncthreads();   // cl reads done before xch region is written in step 0

  // ================= encoder: 50 steps =================
  for (int t = 0; t < TOBS; ++t){
    const int par = t & 1;
    f32x4 acc[2][2];
    #pragma unroll
    for (int rg = 0; rg < 2; ++rg){
      bf16x8 af[4];
      #pragma unroll
      for (int kt = 0; kt < 4; ++kt)
        af[kt] = *(const bf16x8*)&sm.h[par][(rg*16 + cc)*KPAD + kt*32 + qd*8];
      unsigned int po = sm.offsb[t][rg*16 + cc];
      uint4 a5i; a5i.x = q0 ? po : 0u; a5i.y = one_q0; a5i.z = 0u; a5i.w = 0u;
      bf16x8 af5 = __builtin_bit_cast(bf16x8, a5i);
      acc[0][rg] = __builtin_amdgcn_mfma_f32_16x16x32_bf16(af5, b5x[0], zz4, 0,0,0);
      acc[1][rg] = __builtin_amdgcn_mfma_f32_16x16x32_bf16(af5, b5x[1], zz4, 0,0,0);
      #pragma unroll
      for (int kt = 0; kt < 4; ++kt){
        acc[0][rg] = __builtin_amdgcn_mfma_f32_16x16x32_bf16(af[kt], bfr[0][kt], acc[0][rg], 0,0,0);
        acc[1][rg] = __builtin_amdgcn_mfma_f32_16x16x32_bf16(af[kt], bfr[1][kt], acc[1][rg], 0,0,0);
      }
    }
    float ig[2][4];
    if (gs){   // f,o wave: sigmoids -> exchange
      #pragma unroll
      for (int rg = 0; rg < 2; ++rg){
        float sf[4], so[4];
        #pragma unroll
        for (int r = 0; r < 4; ++r){
          float ef = ex2(-acc[0][rg][r] * L2E);
          sf[r] = rcpf(1.0f + ef);
          float eo = ex2(-acc[1][rg][r] * L2E);
          so[r] = rcpf(1.0f + eo);
        }
        *(float4*)&sm.u.xch[j][rg][0][lane][0] = make_float4(sf[0], sf[1], sf[2], sf[3]);
        *(float4*)&sm.u.xch[j][rg][1][lane][0] = make_float4(so[0], so[1], so[2], so[3]);
      }
    } else {   // i,g wave: fused sig(i)*tanh(g) ahead of the exchange barrier
      #pragma unroll
      for (int rg = 0; rg < 2; ++rg)
        #pragma unroll
        for (int r = 0; r < 4; ++r){
          float ei = ex2(-acc[0][rg][r] * L2E);
          float eg = ex2(-acc[1][rg][r] * TL2E);
          float rd = rcpf((1.0f + ei) * (1.0f + eg));
          ig[rg][r] = (1.0f - eg) * rd;
        }
    }
    __syncthreads();
    if (!gs){
      unsigned short* hn = &sm.h[par ^ 1][0];
      #pragma unroll
      for (int rg = 0; rg < 2; ++rg){
        float4 sf = *(const float4*)&sm.u.xch[j][rg][0][lane][0];
        float4 so = *(const float4*)&sm.u.xch[j][rg][1][lane][0];
        float sfa[4] = {sf.x, sf.y, sf.z, sf.w};
        float soa[4] = {so.x, so.y, so.z, so.w};
        #pragma unroll
        for (int r = 0; r < 4; ++r){
          float cn = sfa[r] * cst[rg][r] + ig[rg][r];
          cst[rg][r] = cn;
          float ec = ex2(-cn * TL2E);
          float hr = rcpf(1.0f + ec);
          float th = (1.0f - ec) * hr;
          float hh = soa[r] * th;
          hn[(rg*16 + qd*4 + r)*KPAD + colj] = bfs(hh);
        }
      }
    }
    __syncthreads();
  }
  // hF in sm.h[0]

  // ================= MLP =================
  {
    const int n = wv*16 + cc;          // 256 rows across 16 waves
    float bb1 = bm1[n];
    f32x4 a1[2] = {{bb1,bb1,bb1,bb1},{bb1,bb1,bb1,bb1}};
    bf16x8 af[2][4];
    #pragma unroll
    for (int rg = 0; rg < 2; ++rg)
      #pragma unroll
      for (int kt = 0; kt < 4; ++kt)
        af[rg][kt] = *(const bf16x8*)&sm.h[0][(rg*16 + cc)*KPAD + kt*32 + qd*8];
    #pragma unroll
    for (int kt = 0; kt < 4; ++kt){
      bf16x8 wb = pack8(Wm1 + (size_t)n * HID + kt*32 + qd*8);
      a1[0] = __builtin_amdgcn_mfma_f32_16x16x32_bf16(af[0][kt], wb, a1[0], 0,0,0);
      a1[1] = __builtin_amdgcn_mfma_f32_16x16x32_bf16(af[1][kt], wb, a1[1], 0,0,0);
    }
    #pragma unroll
    for (int rg = 0; rg < 2; ++rg)
      #pragma unroll
      for (int r = 0; r < 4; ++r){
        float v = a1[rg][r]; v = v > 0.f ? v : 0.f;
        sm.u.h1[(rg*16 + qd*4 + r)*H1PAD + n] = bfs(v);
      }
  }
  __syncthreads();
  {
    if (wv < 7){
      const int n2 = wv*16 + cc;       // 112 rows across 7 waves
      float bb2 = bm2[n2];
      f32x4 a2[2] = {{bb2,bb2,bb2,bb2},{bb2,bb2,bb2,bb2}};
      bf16x8 af2[2][8];
      #pragma unroll
      for (int rg = 0; rg < 2; ++rg)
        #pragma unroll
        for (int kt = 0; kt < 8; ++kt)
          af2[rg][kt] = *(const bf16x8*)&sm.u.h1[(rg*16 + cc)*H1PAD + kt*32 + qd*8];
      #pragma unroll
      for (int kt = 0; kt < 8; ++kt){
        bf16x8 wb = pack8(Wm2 + (size_t)n2 * MD + kt*32 + qd*8);
        a2[0] = __builtin_amdgcn_mfma_f32_16x16x32_bf16(af2[0][kt], wb, a2[0], 0,0,0);
        a2[1] = __builtin_amdgcn_mfma_f32_16x16x32_bf16(af2[1][kt], wb, a2[1], 0,0,0);
      }
      #pragma unroll
      for (int rg = 0; rg < 2; ++rg)
        #pragma unroll
        for (int r = 0; r < 4; ++r){
          float v = a2[rg][r]; v = v > 0.f ? v : 0.f;
          sm.h[0][(rg*16 + qd*4 + r)*KPAD + n2] = bfs(v);
        }
    }
    if (tid < ROWS * NZ){
      int row = tid >> 4, nz = tid & 15;
      sm.h[0][row*KPAD + M2N + nz] = bfs(z[(size_t)(R0 + row)*NZ + nz]);
    }
  }
  __syncthreads();   // dh complete in h[0]; h1 reads done -> cl region reusable

  // ================= decoder prep =================
  if (tid < 512){
    const float* wr = Wih_d + tid * EMB;
    float w0 = 0.f, w1 = 0.f, bb = b_d[tid];
    for (int e = 0; e < EMB; ++e){
      float w = wr[e];
      w0 += w * Wd[e*2]; w1 += w * Wd[e*2+1]; bb += w * bd[e];
    }
    sm.u.cl[tid] = make_float4(bb, w0, w1, 0.f);
  }
  const float br0 = br[0], br1 = br[1];
  const float brc = (cc == 0) ? br0 : br1;
  if (wv == 1){    // build Wr readout fragments + step-0 delta
    uint4 bq[4];
    #pragma unroll
    for (int kt = 0; kt < 4; ++kt){
      bf16x8 f = pack8(Wr + (size_t)(cc & 1)*HID + kt*32 + qd*8);
      uint4 uu = __builtin_bit_cast(uint4, f);
      if (cc >= 2){ uu.x = 0u; uu.y = 0u; uu.z = 0u; uu.w = 0u; }
      bq[kt] = uu;
      sm.b5f[lane][kt] = uu;
    }
    #pragma unroll
    for (int rg = 0; rg < 2; ++rg){
      bf16x8 afd[4];
      #pragma unroll
      for (int kt = 0; kt < 4; ++kt)
        afd[kt] = *(const bf16x8*)&sm.h[0][(rg*16 + cc)*KPAD + kt*32 + qd*8];
      f32x4 a5 = zz4;
      #pragma unroll
      for (int kt = 0; kt < 4; ++kt)
        a5 = __builtin_amdgcn_mfma_f32_16x16x32_bf16(afd[kt], __builtin_bit_cast(bf16x8, bq[kt]), a5, 0,0,0);
      if (cc < 2){
        #pragma unroll
        for (int r = 0; r < 4; ++r){
          int row = rg*16 + qd*4 + r;
          sm.delta[row][cc] = sm.offlast[row][cc] - (a5[r] + brc);
        }
      }
    }
  }
  __syncthreads();

  // decoder consts: feedback-folded bias + Whh' = Whh_d + u0(x)Wr0 + u1(x)Wr1
  float w0g[2], w1g[2];
  {
    float4 v0 = sm.u.cl[ga0*128 + colj];
    float4 v1 = sm.u.cl[ga1*128 + colj];
    w0g[0] = v0.y; w1g[0] = v0.z;
    w0g[1] = v1.y; w1g[1] = v1.z;
    float bc0 = v0.x + v0.y*br0 + v0.z*br1;
    float bc1 = v1.x + v1.y*br0 + v1.z*br1;
    uint4 w;
    w.x = q0 ? pkbf(v0.y, v0.z) : 0u; w.y = q0 ? (rnd16(bc0) >> 16) : 0u; w.z = 0u; w.w = 0u;
    b5x[0] = __builtin_bit_cast(bf16x8, w);
    w.x = q0 ? pkbf(v1.y, v1.z) : 0u; w.y = q0 ? (rnd16(bc1) >> 16) : 0u;
    b5x[1] = __builtin_bit_cast(bf16x8, w);
  }
  #pragma unroll
  for (int kt = 0; kt < 4; ++kt){
    const int kb = kt*32 + qd*8;
    float4 wa = *(const float4*)(Wr + kb),       wb2 = *(const float4*)(Wr + kb + 4);
    float4 va = *(const float4*)(Wr + HID + kb), vb2 = *(const float4*)(Wr + HID + kb + 4);
    #pragma unroll
    for (int p = 0; p < 2; ++p){
      const int g = p ? ga1 : ga0;
      const float* pp = Whh_d + (size_t)(g*128 + colj) * HID + kb;
      float4 fa = *(const float4*)pp, fb = *(const float4*)(pp + 4);
      uint4 uu;
      uu.x = pkbf(fa.x + w0g[p]*wa.x  + w1g[p]*va.x,  fa.y + w0g[p]*wa.y  + w1g[p]*va.y);
      uu.y = pkbf(fa.z + w0g[p]*wa.z  + w1g[p]*va.z,  fa.w + w0g[p]*wa.w  + w1g[p]*va.w);
      uu.z = pkbf(fb.x + w0g[p]*wb2.x + w1g[p]*vb2.x, fb.y + w0g[p]*wb2.y + w1g[p]*vb2.y);
      uu.w = pkbf(fb.z + w0g[p]*wb2.z + w1g[p]*vb2.z, fb.w + w0g[p]*wb2.w + w1g[p]*vb2.w);
      bfr[p][kt] = __builtin_bit_cast(bf16x8, uu);
    }
  }
  // step-0 delta A-fragments (per rg) and steady {0,0,1}
  uint4 c5; c5.x = 0u; c5.y = one_q0; c5.z = 0u; c5.w = 0u;
  const bf16x8 af5c = __builtin_bit_cast(bf16x8, c5);
  bf16x8 af5cur[2];
  {
    float2 dv0 = *(const float2*)&sm.delta[cc][0];
    float2 dv1 = *(const float2*)&sm.delta[16 + cc][0];
    uint4 d0 = c5; d0.x = q0 ? pkbf(dv0.x, dv0.y) : 0u;
    uint4 d1 = c5; d1.x = q0 ? pkbf(dv1.x, dv1.y) : 0u;
    af5cur[0] = __builtin_bit_cast(bf16x8, d0);
    af5cur[1] = __builtin_bit_cast(bf16x8, d1);
  }
  float cum[2][4];
  #pragma unroll
  for (int rg = 0; rg < 2; ++rg)
    #pragma unroll
    for (int r = 0; r < 4; ++r) cum[rg][r] = 0.f;
  if (wv == 1 && cc < 2){
    #pragma unroll
    for (int rg = 0; rg < 2; ++rg)
      #pragma unroll
      for (int r = 0; r < 4; ++r)
        cum[rg][r] = obs[(size_t)(R0 + rg*16 + qd*4 + r)*(TOBS*2) + (TOBS-1)*2 + cc];
  }
  #pragma unroll
  for (int rg = 0; rg < 2; ++rg)
    #pragma unroll
    for (int r = 0; r < 4; ++r) cst[rg][r] = 0.f;
  __syncthreads();   // cl reads done before xch region written again

  // ================= decoder: 100 steps =================
  for (int s = 0; s < SDEC; ++s){
    const int par = s & 1;
    f32x4 acc[2][2];
    #pragma unroll
    for (int rg = 0; rg < 2; ++rg){
      bf16x8 af[4];
      #pragma unroll
      for (int kt = 0; kt < 4; ++kt)
        af[kt] = *(const bf16x8*)&sm.h[par][(rg*16 + cc)*KPAD + kt*32 + qd*8];
      acc[0][rg] = __builtin_amdgcn_mfma_f32_16x16x32_bf16(af5cur[rg], b5x[0], zz4, 0,0,0);
      acc[1][rg] = __builtin_amdgcn_mfma_f32_16x16x32_bf16(af5cur[rg], b5x[1], zz4, 0,0,0);
      #pragma unroll
      for (int kt = 0; kt < 4; ++kt){
        acc[0][rg] = __builtin_amdgcn_mfma_f32_16x16x32_bf16(af[kt], bfr[0][kt], acc[0][rg], 0,0,0);
        acc[1][rg] = __builtin_amdgcn_mfma_f32_16x16x32_bf16(af[kt], bfr[1][kt], acc[1][rg], 0,0,0);
      }
      if (wv == 1 && s > 0){    // readout of h_{s-1}: off = Wr.h + br, cumsum, store
        f32x4 a5 = {brc, brc, brc, brc};
        #pragma unroll
        for (int kt = 0; kt < 4; ++kt){
          uint4 bq = sm.b5f[lane][kt];
          a5 = __builtin_amdgcn_mfma_f32_16x16x32_bf16(af[kt], __builtin_bit_cast(bf16x8, bq), a5, 0,0,0);
        }
        if (cc < 2){
          #pragma unroll
          for (int r = 0; r < 4; ++r){
            cum[rg][r] += a5[r];
            out[((size_t)(R0 + rg*16 + qd*4 + r)*SDEC + (s-1))*2 + cc] = cum[rg][r];
          }
        }
      }
    }
    af5cur[0] = af5c; af5cur[1] = af5c;

    float ig[2][4];
    if (gs){
      #pragma unroll
      for (int rg = 0; rg < 2; ++rg){
        float sf[4], so[4];
        #pragma unroll
        for (int r = 0; r < 4; ++r){
          float ef = ex2(-acc[0][rg][r] * L2E);
          sf[r] = rcpf(1.0f + ef);
          float eo = ex2(-acc[1][rg][r] * L2E);
          so[r] = rcpf(1.0f + eo);
        }
        *(float4*)&sm.u.xch[j][rg][0][lane][0] = make_float4(sf[0], sf[1], sf[2], sf[3]);
        *(float4*)&sm.u.xch[j][rg][1][lane][0] = make_float4(so[0], so[1], so[2], so[3]);
      }
    } else {
      #pragma unroll
      for (int rg = 0; rg < 2; ++rg)
        #pragma unroll
        for (int r = 0; r < 4; ++r){
          float ei = ex2(-acc[0][rg][r] * L2E);
          float eg = ex2(-acc[1][rg][r] * TL2E);
          float rd = rcpf((1.0f + ei) * (1.0f + eg));
          ig[rg][r] = (1.0f - eg) * rd;
        }
    }
    __syncthreads();
    if (!gs){
      unsigned short* hn = &sm.h[par ^ 1][0];
      #pragma unroll
      for (int rg = 0; rg < 2; ++rg){
        float4 sf = *(const float4*)&sm.u.xch[j][rg][0][lane][0];
        float4 so = *(const float4*)&sm.u.xch[j][rg][1][lane][0];
        float sfa[4] = {sf.x, sf.y, sf.z, sf.w};
        float soa[4] = {so.x, so.y, so.z, so.w};
        #pragma unroll
        for (int r = 0; r < 4; ++r){
          float cn = sfa[r] * cst[rg][r] + ig[rg][r];
          cst[rg][r] = cn;
          float ec = ex2(-cn * TL2E);
          float hr = rcpf(1.0f + ec);
          float th = (1.0f - ec) * hr;
          float hh = soa[r] * th;
          hn[(rg*16 + qd*4 + r)*KPAD + colj] = bfs(hh);
        }
      }
    }
    __syncthreads();
  }

  // epilogue: pred[S-1] from h[0] (= h_{S-1})
  if (wv == 1){
    #pragma unroll
    for (int rg = 0; rg < 2; ++rg){
      bf16x8 af[4];
      #pragma unroll
      for (int kt = 0; kt < 4; ++kt)
        af[kt] = *(const bf16x8*)&sm.h[0][(rg*16 + cc)*KPAD + kt*32 + qd*8];
      f32x4 a5 = {brc, brc, brc, brc};
      #pragma unroll
      for (int kt = 0; kt < 4; ++kt){
        uint4 bq = sm.b5f[lane][kt];
        a5 = __builtin_amdgcn_mfma_f32_16x16x32_bf16(af[kt], __builtin_bit_cast(bf16x8, bq), a5, 0,0,0);
      }
      if (cc < 2){
        #pragma unroll
        for (int r = 0; r < 4; ++r){
          cum[rg][r] += a5[r];
          out[((size_t)(R0 + rg*16 + qd*4 + r)*SDEC + (SDEC-1))*2 + cc] = cum[rg][r];
        }
      }
    }
  }
}

extern "C" void kernel_launch(void* const* d_in, const int* in_sizes, int n_in,
                              void* d_out, int out_size, void* d_ws, size_t ws_size,
                              hipStream_t stream) {
  (void)in_sizes; (void)n_in; (void)d_ws; (void)ws_size; (void)out_size;
  const float* obs   = (const float*)d_in[0];
  // d_in[1] = num_steps (100), compile-time constant here
  const float* We    = (const float*)d_in[2];
  const float* be    = (const float*)d_in[3];
  const float* Wih_e = (const float*)d_in[4];
  const float* Whh_e = (const float*)d_in[5];
  const float* b_e   = (const float*)d_in[6];
  const float* Wm1   = (const float*)d_in[7];
  const float* bm1   = (const float*)d_in[8];
  const float* Wm2   = (const float*)d_in[9];
  const float* bm2   = (const float*)d_in[10];
  const float* Wd    = (const float*)d_in[11];
  const float* bd    = (const float*)d_in[12];
  const float* Wih_d = (const float*)d_in[13];
  const float* Whh_d = (const float*)d_in[14];
  const float* b_d   = (const float*)d_in[15];
  const float* Wr    = (const float*)d_in[16];
  const float* br    = (const float*)d_in[17];
  const float* zz    = (const float*)d_in[18];
  hipLaunchKernelGGL(seqgen, dim3(8192 / ROWS), dim3(1024), 0, stream,
                     obs, We, be, Wih_e, Whh_e, b_e, Wm1, bm1, Wm2, bm2,
                     Wd, bd, Wih_d, Whh_d, b_d, Wr, br, zz, (float*)d_out);
}